// Round 16
// baseline (208.260 us; speedup 1.0000x reference)
//
#include <hip/hip_runtime.h>
#include <hip/hip_bf16.h>

#define A_TOTAL  200000
#define N_NODES  50000
#define NT_NODES 49998     // unique regular triples: t in [0, N-2)
#define BSEG     100
#define FR_      256
#define DIN_     512
#define H_       256
#define P_       6
#define TA       32
#define NTHREADS 256

#define SNI_STRIDE 1040   // 512 bf16 = 1024B + 16B pad
#define SH_STRIDE  528    // 256 bf16 = 512B + 16B pad

typedef float f32x16 __attribute__((ext_vector_type(16)));
typedef short bf16x8 __attribute__((ext_vector_type(8)));

__device__ __forceinline__ unsigned short f2bf(float x) {
    union { float f; unsigned int u; } c; c.f = x;
    unsigned int u = c.u;
    return (unsigned short)((u + 0x7fffu + ((u >> 16) & 1u)) >> 16);
}
__device__ __forceinline__ unsigned int pk2(float a, float b) {   // v_cvt_pk_bf16_f32
    union { __hip_bfloat162 h2; unsigned int u; } c;
    c.h2 = __float22bfloat162_rn(float2{a, b});
    return c.u;
}
__device__ __forceinline__ float fast_tanh(float x) {
    float e = __builtin_amdgcn_exp2f(x * 2.88539008177793f);  // e^{2x}
    float r = __builtin_amdgcn_rcpf(e + 1.f);
    return __builtin_fmaf(-2.f, r, 1.f);
}
__device__ __forceinline__ f32x16 mfma32(bf16x8 a, bf16x8 b, f32x16 c) {
    return __builtin_amdgcn_mfma_f32_32x32x16_bf16(a, b, c, 0, 0, 0);
}

// VALU-pipe 16-lane sum via DPP row rotate; + one shfl_xor(16) for 32-lane.
#define DPP_ROR_ADD(v, CTRL)                                                      \
    do { union { float f; int i; } _s, _d; _s.f = (v);                            \
         _d.i = __builtin_amdgcn_update_dpp(0, _s.i, (CTRL), 0xf, 0xf, false);    \
         (v) += _d.f; } while (0)
#define DPP_SUM16(v) { DPP_ROR_ADD(v, 0x121); DPP_ROR_ADD(v, 0x122); \
                       DPP_ROR_ADD(v, 0x124); DPP_ROR_ADD(v, 0x128); }

// ---------------------------------------------------------------------------
// Prep: W1/W2 -> bf16 32x32x16-B-fragment-linear; prefix-sum; zero out.
// B-frag: lane l holds B[k = kstep*16 + 8*(l>>5) + j][n = ntile*32 + (l&31)]
// stored wt[p][kstep][ntile(8)][lane][j]  (4096 elems per kstep).
// ---------------------------------------------------------------------------
__global__ void prep_kernel(const float* __restrict__ W1, const float* __restrict__ W2,
                            const int* __restrict__ num_angles, float* __restrict__ out,
                            int* __restrict__ prefix,
                            unsigned short* __restrict__ wt1, unsigned short* __restrict__ wt2) {
    int tt = blockIdx.x * blockDim.x + threadIdx.x;
    if (blockIdx.x == 0) {
        if (threadIdx.x < BSEG) out[threadIdx.x] = 0.f;
        if (threadIdx.x == 0) {
            int acc = 0; prefix[0] = 0;
            for (int i = 0; i < BSEG; ++i) { acc += num_angles[i]; prefix[i + 1] = acc; }
        }
    }
    if (tt < 98304) {                       // W1: 6 p * 32 kstep * 8 ntile * 64 lanes
        int l  = tt & 63;
        int nt = (tt >> 6) & 7;
        int ks = (tt >> 9) & 31;
        int p  = tt >> 14;
        int k  = ks * 16 + 8 * (l >> 5);
        int n  = nt * 32 + (l & 31);
        const float* src = W1 + ((size_t)p * DIN_ + k) * H_ + n;
        unsigned short tmp[8];
#pragma unroll
        for (int j = 0; j < 8; ++j) tmp[j] = f2bf(src[(size_t)j * H_]);
        *reinterpret_cast<uint4*>(wt1 + (size_t)tt * 8) = *reinterpret_cast<uint4*>(tmp);
    } else if (tt < 98304 + 49152) {        // W2: 6 p * 16 kstep * 8 ntile * 64 lanes
        int t2 = tt - 98304;
        int l  = t2 & 63;
        int nt = (t2 >> 6) & 7;
        int ks = (t2 >> 9) & 15;
        int p  = t2 >> 13;
        int k  = ks * 16 + 8 * (l >> 5);
        int n  = nt * 32 + (l & 31);
        const float* src = W2 + ((size_t)p * H_ + k) * H_ + n;
        unsigned short tmp[8];
#pragma unroll
        for (int j = 0; j < 8; ++j) tmp[j] = f2bf(src[(size_t)j * H_]);
        *reinterpret_cast<uint4*>(wt2 + (size_t)t2 * 8) = *reinterpret_cast<uint4*>(tmp);
    }
}

// Load the wave's 2 ntiles of kstep s (4096-elem blocks).
#define LD2(dst, bp, s)                                                          \
    { dst[0] = *(const bf16x8*)((bp) + (size_t)(s) * 4096);                      \
      dst[1] = *(const bf16x8*)((bp) + (size_t)(s) * 4096 + 512); }

// One k-step: prefetch s+3 into UP, ONE A-read feeds TWO fat 32x32 MFMAs.
#define GSTEP32(s, SMAX, UC, UP, bp, aBase, ac)                                  \
    { if ((s) + 3 < (SMAX)) LD2(UP, bp, (s) + 3);                                \
      bf16x8 a0 = *(const bf16x8*)((aBase) + 32 * (s));                          \
      ac[0] = mfma32(a0, UC[0], ac[0]);                                          \
      ac[1] = mfma32(a0, UC[1], ac[1]); }

#define G4(s, SMAX, bp, aBase, ac)                                               \
    GSTEP32((s) + 0, SMAX, u0, u3, bp, aBase, ac);                               \
    GSTEP32((s) + 1, SMAX, u1, u0, bp, aBase, ac);                               \
    GSTEP32((s) + 2, SMAX, u2, u1, bp, aBase, ac);                               \
    GSTEP32((s) + 3, SMAX, u3, u2, bp, aBase, ac);

// ---------------------------------------------------------------------------
// Table kernel, 32x32x16 engine: 256 threads = 4 waves x (32 rows x 64 cols).
// Per k-step: 1 ds_read_b128 + 2 global B-loads + 2 MFMA (half the MFMA
// instruction count of the 16x16 engine, -20% MFMA cycles). XOR bit-4 swizzle
// on the k-byte (bit from row>>3) cuts 32-row column reads 4-way -> 2-way.
// LDS ~51 KB -> 3 blocks/CU.
// ---------------------------------------------------------------------------
__global__ __launch_bounds__(NTHREADS, 3)
void table_main(const float* __restrict__ r, const float* __restrict__ xyz,
                const float* __restrict__ b1, const float* __restrict__ b2,
                const float* __restrict__ W3, const float* __restrict__ b3,
                float* __restrict__ Etab,
                const unsigned short* __restrict__ wt1, const unsigned short* __restrict__ wt2) {
    __shared__ __align__(16) char cNI[TA * SNI_STRIDE];  // 33280 B
    __shared__ __align__(16) char cH[TA * SH_STRIDE];    // 16896 B
    __shared__ float sOut[P_ * TA];                      // 768 B

    const int tid  = threadIdx.x;
    const int lane = tid & 63;
    const int w    = tid >> 6;        // wave 0..3: cols [w*64, w*64+64)
    const int aB   = blockIdx.x * TA; // node-row base
    const int rA   = lane & 31;       // A-frag row
    const int hi   = lane >> 5;       // k-subgroup
    const int swzA = (16 * hi) ^ (((rA >> 3) & 1) << 4);  // XORed k-base

    if (tid < P_ * TA) sOut[tid] = 0.f;

    const unsigned short* bofs1 = wt1 + (size_t)w * 1024 + (size_t)lane * 8;
    const unsigned short* bofs2 = wt2 + (size_t)w * 1024 + (size_t)lane * 8;
    bf16x8 u0[2], u1[2], u2[2], u3[2];   // rotating B buffers (live across barriers)

    // Hoist p=0 L1 k0-k2 above the staging + barrier.
    LD2(u0, bofs1, 0);
    LD2(u1, bofs1, 1);
    LD2(u2, bofs1, 2);

    // ---- stage node_input row t = [r[t]+r[t+2], r[t+1]] -> LDS bf16 ----
#pragma unroll
    for (int it = 0; it < 8; ++it) {
        int c   = it * NTHREADS + tid;       // 2048 chunks of 8 elems
        int row = c >> 6;
        int k0  = (c & 63) * 8;
        int t   = min(aB + row, NT_NODES - 1);   // tail rows: dup (discarded)
        float v[8];
        if (k0 < FR_) {
            const float4* p0 = (const float4*)(r + (size_t)t * FR_ + k0);
            const float4* p2 = (const float4*)(r + (size_t)(t + 2) * FR_ + k0);
            float4 x0 = p0[0], x1 = p0[1], y0 = p2[0], y1 = p2[1];
            v[0] = x0.x + y0.x; v[1] = x0.y + y0.y; v[2] = x0.z + y0.z; v[3] = x0.w + y0.w;
            v[4] = x1.x + y1.x; v[5] = x1.y + y1.y; v[6] = x1.z + y1.z; v[7] = x1.w + y1.w;
        } else {
            const float4* p1 = (const float4*)(r + (size_t)(t + 1) * FR_ + (k0 - FR_));
            float4 x0 = p1[0], x1 = p1[1];
            v[0] = x0.x; v[1] = x0.y; v[2] = x0.z; v[3] = x0.w;
            v[4] = x1.x; v[5] = x1.y; v[6] = x1.z; v[7] = x1.w;
        }
        uint4 pk;
        pk.x = pk2(v[0], v[1]); pk.y = pk2(v[2], v[3]);
        pk.z = pk2(v[4], v[5]); pk.w = pk2(v[6], v[7]);
        int dst = row * SNI_STRIDE + ((k0 * 2) ^ (((row >> 3) & 1) << 4));
        *reinterpret_cast<uint4*>(cNI + dst) = pk;
    }
    __syncthreads();

    for (int p = 0; p < P_; ++p) {
        const unsigned short* bp1 = bofs1 + (size_t)p * 131072;
        const unsigned short* bp2 = bofs2 + (size_t)p * 65536;
        const int col0 = w * 64 + rA;          // tile-0 col
        const int col1 = w * 64 + 32 + rA;     // tile-1 col

        // ---------------- layer 1: [32x512] @ [512x256], 64 cols/wave ----
        f32x16 acc[2];
        {
            float ba = b1[p * H_ + col0], bb = b1[p * H_ + col1];
#pragma unroll
            for (int i = 0; i < 16; ++i) { acc[0][i] = ba; acc[1][i] = bb; }
        }
        {
            const char* aBase = cNI + rA * SNI_STRIDE + swzA;
            G4( 0, 32, bp1, aBase, acc);
            G4( 4, 32, bp1, aBase, acc);
            G4( 8, 32, bp1, aBase, acc);
            G4(12, 32, bp1, aBase, acc);
            G4(16, 32, bp1, aBase, acc);
            G4(20, 32, bp1, aBase, acc);
            G4(24, 32, bp1, aBase, acc);
            G4(28, 32, bp1, aBase, acc);
        }
        // Hoist L2 k0-k2 above the tanh epilogue + barrier.
        LD2(u0, bp2, 0);
        LD2(u1, bp2, 1);
        LD2(u2, bp2, 2);
        {   // tanh + bf16 -> cH. D: col=l&31 (per tile), row=(r&3)+8*(r>>2)+4*hi
#pragma unroll
            for (int nt = 0; nt < 2; ++nt) {
                int colb = ((nt ? col1 : col0) * 2);
#pragma unroll
                for (int rg = 0; rg < 8; ++rg) {       // pairs (2rg, 2rg+1)
                    float t0 = fast_tanh(acc[nt][2 * rg]);
                    float t1 = fast_tanh(acc[nt][2 * rg + 1]);
                    unsigned int u01 = pk2(t0, t1);
                    int row0 = ((2 * rg) & 3) + 8 * ((2 * rg) >> 2) + 4 * hi;
                    char* b0 = cH + row0 * SH_STRIDE + (colb ^ (((row0 >> 3) & 1) << 4));
                    int row1 = row0 + 1;               // (2rg+1)&3 = (2rg&3)+1
                    char* b1p = cH + row1 * SH_STRIDE + (colb ^ (((row1 >> 3) & 1) << 4));
                    *(unsigned short*)b0  = (unsigned short)(u01 & 0xffff);
                    *(unsigned short*)b1p = (unsigned short)(u01 >> 16);
                }
            }
        }
        __syncthreads();

        // ---------------- layer 2: [32x256] @ [256x256] ----------------
        f32x16 acc2[2];
        {
            float ba = b2[p * H_ + col0], bb = b2[p * H_ + col1];
#pragma unroll
            for (int i = 0; i < 16; ++i) { acc2[0][i] = ba; acc2[1][i] = bb; }
        }
        {
            const char* aBase = cH + rA * SH_STRIDE + swzA;
            G4( 0, 16, bp2, aBase, acc2);
            G4( 4, 16, bp2, aBase, acc2);
            G4( 8, 16, bp2, aBase, acc2);
            G4(12, 16, bp2, aBase, acc2);
        }
        // Hoist next-p L1 k0-k2 above the layer-3 epilogue + barrier.
        if (p < P_ - 1) {
            LD2(u0, bp1 + 131072, 0);
            LD2(u1, bp1 + 131072, 1);
            LD2(u2, bp1 + 131072, 2);
        }

        // ---- layer 3: combine tiles, 32-lane reduce (DPP16 + shfl16) ----
        {
            float wv0 = W3[p * H_ + col0];
            float wv1 = W3[p * H_ + col1];
            float vals[16];
#pragma unroll
            for (int i = 0; i < 16; ++i)
                vals[i] = fast_tanh(acc2[0][i]) * wv0 + fast_tanh(acc2[1][i]) * wv1;
#pragma unroll
            for (int i = 0; i < 16; ++i) {
                DPP_SUM16(vals[i]);
                vals[i] += __shfl_xor(vals[i], 16);
            }
            if (rA == 0) {
#pragma unroll
                for (int i = 0; i < 16; ++i) {
                    int row = (i & 3) + 8 * (i >> 2) + 4 * hi;
                    atomicAdd(&sOut[p * TA + row], vals[i]);
                }
            }
        }
        __syncthreads();   // cH reads done (next p overwrites) + sOut[p] visible
    }

    // ---------------- geometry + energy -> Etab[t] ----------------
    if (tid < TA && (aB + tid) < NT_NODES) {
        int t = aB + tid;
        float ax = xyz[3 * t],     ay = xyz[3 * t + 1], az = xyz[3 * t + 2];
        float bx = xyz[3 * t + 3], by = xyz[3 * t + 4], bz = xyz[3 * t + 5];
        float cx = xyz[3 * t + 6], cy = xyz[3 * t + 7], cz = xyz[3 * t + 8];
        float v1x = bx - ax, v1y = by - ay, v1z = bz - az;
        float v2x = cx - bx, v2y = cy - by, v2z = cz - bz;
        float dot = -(v1x * v2x + v1y * v2y + v1z * v2z);
        float n1  = v1x * v1x + v1y * v1y + v1z * v1z;
        float n2  = v2x * v2x + v2y * v2y + v2z * v2z;
        float th  = acosf((dot / sqrtf(n1 * n2)) / 1.000001f);

        float o0 = sOut[0 * TA + tid] + b3[0], o1 = sOut[1 * TA + tid] + b3[1];
        float o2 = sOut[2 * TA + tid] + b3[2], o3 = sOut[3 * TA + tid] + b3[3];
        float o4 = sOut[4 * TA + tid] + b3[4], o5 = sOut[5 * TA + tid] + b3[5];
        float t0h = (1.38243827f + o0); t0h *= t0h;
        float kh  = (3.16227766f + o1); kh  *= kh;
        float d   = th - t0h;
        float E   = 0.5f * kh * d * d;
        float t0c = o2 * o2, kc = o3 * o3;
        float dc  = th - t0c;
        E += 0.5f * kc * dc * dc * dc;
        float t0q = o4 * o4, kq = o5 * o5;
        float dq  = th - t0q;
        E += 0.5f * kq * dq * dq * dq * dq;
        Etab[t] = E;
    }
}

// ---------------------------------------------------------------------------
// Per-angle pass: regular angles take E from the table, bin into LDS segments.
// ---------------------------------------------------------------------------
#define SEG_ANG 2048
__global__ void seg_kernel(const int* __restrict__ ang, const float* __restrict__ Etab,
                           const int* __restrict__ prefix, float* __restrict__ out) {
    __shared__ float sSeg[BSEG];
    __shared__ int   sPre[BSEG + 1];
    int tid = threadIdx.x;
    if (tid < BSEG) sSeg[tid] = 0.f;
    if (tid <= BSEG) sPre[tid] = prefix[tid];
    __syncthreads();
    int base = blockIdx.x * SEG_ANG;
#pragma unroll
    for (int i = 0; i < SEG_ANG / 256; ++i) {
        int a = base + i * 256 + tid;
        if (a < A_TOTAL) {
            int i0 = ang[3 * a], i1 = ang[3 * a + 1], i2 = ang[3 * a + 2];
            if (i1 == i0 + 1 && i2 == i0 + 2 && i0 >= 0 && i0 < NT_NODES) {
                float E = Etab[i0];
                int lo = 0, hi = BSEG - 1;
                while (lo < hi) { int mid = (lo + hi + 1) >> 1; if (sPre[mid] <= a) lo = mid; else hi = mid - 1; }
                atomicAdd(&sSeg[lo], E);
            }
        }
    }
    __syncthreads();
    if (tid < BSEG) {
        float v = sSeg[tid];
        if (v != 0.f) atomicAdd(out + tid, v);
    }
}

// ---------------------------------------------------------------------------
// Fallback: any non-regular angle gets an exact scalar f32 MLP (never
// triggers for this generator; keeps arbitrary-input correctness).
// ---------------------------------------------------------------------------
__global__ void fb_kernel(const float* __restrict__ r, const float* __restrict__ xyz,
                          const int* __restrict__ ang,
                          const float* __restrict__ W1, const float* __restrict__ b1,
                          const float* __restrict__ W2, const float* __restrict__ b2,
                          const float* __restrict__ W3, const float* __restrict__ b3,
                          const int* __restrict__ prefix, float* __restrict__ out) {
    int gid = blockIdx.x * blockDim.x + threadIdx.x;
    int stride = gridDim.x * blockDim.x;
    for (int a = gid; a < A_TOTAL; a += stride) {
        int i0 = ang[3 * a], i1 = ang[3 * a + 1], i2 = ang[3 * a + 2];
        if (i1 == i0 + 1 && i2 == i0 + 2 && i0 >= 0 && i0 < NT_NODES) continue;  // table path
        float ni[DIN_];
        for (int k = 0; k < FR_; ++k) ni[k] = r[(size_t)i0 * FR_ + k] + r[(size_t)i2 * FR_ + k];
        for (int k = 0; k < FR_; ++k) ni[FR_ + k] = r[(size_t)i1 * FR_ + k];
        float o[P_];
        for (int p = 0; p < P_; ++p) {
            float h1[H_], h2[H_];
            for (int j = 0; j < H_; ++j) {
                float s = b1[p * H_ + j];
                for (int i = 0; i < DIN_; ++i) s += ni[i] * W1[((size_t)p * DIN_ + i) * H_ + j];
                h1[j] = tanhf(s);
            }
            for (int j = 0; j < H_; ++j) {
                float s = b2[p * H_ + j];
                for (int i = 0; i < H_; ++i) s += h1[i] * W2[((size_t)p * H_ + i) * H_ + j];
                h2[j] = tanhf(s);
            }
            float s = b3[p];
            for (int i = 0; i < H_; ++i) s += h2[i] * W3[p * H_ + i];
            o[p] = s;
        }
        float ax = xyz[3 * i0], ay = xyz[3 * i0 + 1], az = xyz[3 * i0 + 2];
        float bx = xyz[3 * i1], by = xyz[3 * i1 + 1], bz = xyz[3 * i1 + 2];
        float cx = xyz[3 * i2], cy = xyz[3 * i2 + 1], cz = xyz[3 * i2 + 2];
        float v1x = bx - ax, v1y = by - ay, v1z = bz - az;
        float v2x = cx - bx, v2y = cy - by, v2z = cz - bz;
        float dot = -(v1x * v2x + v1y * v2y + v1z * v2z);
        float n1  = v1x * v1x + v1y * v1y + v1z * v1z;
        float n2  = v2x * v2x + v2y * v2y + v2z * v2z;
        float th  = acosf((dot / sqrtf(n1 * n2)) / 1.000001f);
        float t0h = (1.38243827f + o[0]); t0h *= t0h;
        float kh  = (3.16227766f + o[1]); kh  *= kh;
        float d   = th - t0h;
        float E   = 0.5f * kh * d * d;
        float t0c = o[2] * o[2], kc = o[3] * o[3];
        float dc  = th - t0c;
        E += 0.5f * kc * dc * dc * dc;
        float t0q = o[4] * o[4], kq = o[5] * o[5];
        float dq  = th - t0q;
        E += 0.5f * kq * dq * dq * dq * dq;
        int lo = 0, hi = BSEG - 1;
        while (lo < hi) { int mid = (lo + hi + 1) >> 1; if (prefix[mid] <= a) lo = mid; else hi = mid - 1; }
        atomicAdd(out + lo, E);
    }
}

extern "C" void kernel_launch(void* const* d_in, const int* in_sizes, int n_in,
                              void* d_out, int out_size, void* d_ws, size_t ws_size,
                              hipStream_t stream) {
    const float* r   = (const float*)d_in[0];
    const float* xyz = (const float*)d_in[1];
    const int*   ang = (const int*)d_in[2];
    const int*   na  = (const int*)d_in[3];
    const float* W1  = (const float*)d_in[4];
    const float* b1  = (const float*)d_in[5];
    const float* W2  = (const float*)d_in[6];
    const float* b2  = (const float*)d_in[7];
    const float* W3  = (const float*)d_in[8];
    const float* b3  = (const float*)d_in[9];
    float* out = (float*)d_out;

    char* ws = (char*)d_ws;
    int* prefix          = (int*)ws;                                        // 101 ints
    unsigned short* wt1  = (unsigned short*)(ws + 512);                     // 1.5 MB
    unsigned short* wt2  = (unsigned short*)(ws + 512 + 1572864);           // 0.75 MB
    float* Etab          = (float*)(ws + 512 + 1572864 + 786432);           // 200 KB

    prep_kernel<<<576, 256, 0, stream>>>(W1, W2, na, out, prefix, wt1, wt2);
    int nblk = (NT_NODES + TA - 1) / TA;   // 1563 blocks over unique triples
    table_main<<<nblk, NTHREADS, 0, stream>>>(r, xyz, b1, b2, W3, b3, Etab, wt1, wt2);
    seg_kernel<<<(A_TOTAL + SEG_ANG - 1) / SEG_ANG, 256, 0, stream>>>(ang, Etab, prefix, out);
    fb_kernel<<<32, 256, 0, stream>>>(r, xyz, ang, W1, b1, W2, b2, W3, b3, prefix, out);
}

// Round 17
// 182.218 us; speedup vs baseline: 1.1429x; 1.1429x over previous
//
#include <hip/hip_runtime.h>
#include <hip/hip_bf16.h>

#define A_TOTAL  200000
#define N_NODES  50000
#define NT_NODES 49998     // unique regular triples: t in [0, N-2)
#define BSEG     100
#define FR_      256
#define DIN_     512
#define H_       256
#define P_       6
#define TA       48
#define NTHREADS 512

#define SNI_STRIDE 1040   // 512 bf16 = 1024B + 16B pad
#define SH_STRIDE  528    // 256 bf16 = 512B + 16B pad

typedef float f32x4  __attribute__((ext_vector_type(4)));
typedef short bf16x8 __attribute__((ext_vector_type(8)));

__device__ __forceinline__ unsigned short f2bf(float x) {
    union { float f; unsigned int u; } c; c.f = x;
    unsigned int u = c.u;
    return (unsigned short)((u + 0x7fffu + ((u >> 16) & 1u)) >> 16);
}
__device__ __forceinline__ unsigned int pk2(float a, float b) {   // v_cvt_pk_bf16_f32
    union { __hip_bfloat162 h2; unsigned int u; } c;
    c.h2 = __float22bfloat162_rn(float2{a, b});
    return c.u;
}
__device__ __forceinline__ float fast_tanh(float x) {
    float e = __builtin_amdgcn_exp2f(x * 2.88539008177793f);  // e^{2x}
    float r = __builtin_amdgcn_rcpf(e + 1.f);
    return __builtin_fmaf(-2.f, r, 1.f);
}
__device__ __forceinline__ f32x4 mfma16(bf16x8 a, bf16x8 b, f32x4 c) {
    return __builtin_amdgcn_mfma_f32_16x16x32_bf16(a, b, c, 0, 0, 0);
}

// VALU-pipe 16-lane sum via DPP row rotate (off the LDS pipe).
#define DPP_ROR_ADD(v, CTRL)                                                      \
    do { union { float f; int i; } _s, _d; _s.f = (v);                            \
         _d.i = __builtin_amdgcn_update_dpp(0, _s.i, (CTRL), 0xf, 0xf, false);    \
         (v) += _d.f; } while (0)
#define DPP_SUM16(v) { DPP_ROR_ADD(v, 0x121); DPP_ROR_ADD(v, 0x122); \
                       DPP_ROR_ADD(v, 0x124); DPP_ROR_ADD(v, 0x128); }

// ---------------------------------------------------------------------------
// Prep: W1/W2 -> bf16 fragment-linear layout; prefix-sum num_angles; zero out.
// B-frag for 16x16x32: lane l holds B[k = s*32 + 8*(l>>4) + j][n = nt*16 + (l&15)]
// stored as wt[p][s][ntile][lane][j] (16B/lane -> coalesced 1KB wave loads).
// ---------------------------------------------------------------------------
__global__ void prep_kernel(const float* __restrict__ W1, const float* __restrict__ W2,
                            const int* __restrict__ num_angles, float* __restrict__ out,
                            int* __restrict__ prefix,
                            unsigned short* __restrict__ wt1, unsigned short* __restrict__ wt2) {
    int tt = blockIdx.x * blockDim.x + threadIdx.x;
    if (blockIdx.x == 0) {
        if (threadIdx.x < BSEG) out[threadIdx.x] = 0.f;
        if (threadIdx.x == 0) {
            int acc = 0; prefix[0] = 0;
            for (int i = 0; i < BSEG; ++i) { acc += num_angles[i]; prefix[i + 1] = acc; }
        }
    }
    if (tt < 98304) {                       // W1: 6 p * 16 s * 16 nt * 64 lanes
        int l  = tt & 63;
        int nt = (tt >> 6) & 15;
        int s  = (tt >> 10) & 15;
        int p  = tt >> 14;
        int k  = s * 32 + 8 * (l >> 4);
        int n  = nt * 16 + (l & 15);
        const float* src = W1 + ((size_t)p * DIN_ + k) * H_ + n;
        unsigned short tmp[8];
#pragma unroll
        for (int j = 0; j < 8; ++j) tmp[j] = f2bf(src[(size_t)j * H_]);
        *reinterpret_cast<uint4*>(wt1 + (size_t)tt * 8) = *reinterpret_cast<uint4*>(tmp);
    } else if (tt < 98304 + 49152) {        // W2: 6 p * 8 s * 16 nt * 64 lanes
        int t2 = tt - 98304;
        int l  = t2 & 63;
        int nt = (t2 >> 6) & 15;
        int s  = (t2 >> 10) & 7;
        int p  = t2 >> 13;
        int k  = s * 32 + 8 * (l >> 4);
        int n  = nt * 16 + (l & 15);
        const float* src = W2 + ((size_t)p * H_ + k) * H_ + n;
        unsigned short tmp[8];
#pragma unroll
        for (int j = 0; j < 8; ++j) tmp[j] = f2bf(src[(size_t)j * H_]);
        *reinterpret_cast<uint4*>(wt2 + (size_t)t2 * 8) = *reinterpret_cast<uint4*>(tmp);
    }
}

// Load the 2 ntiles of s-step s for this wave into a 2-frag buffer.
#define LD2(dst, bp, s)                                                          \
    { dst[0] = *(const bf16x8*)((bp) + (size_t)(s) * 8192);                      \
      dst[1] = *(const bf16x8*)((bp) + (size_t)(s) * 8192 + 512); }

// One s-step: prefetch s+5 into UP (distance-5, 6-buffer rotation),
// 3 A-reads, 6 MFMA (6 independent accumulator chains).
#define GSTEP(s, SMAX, UC, UP, bp, aBase, STRIDE, ac)                            \
    { if ((s) + 5 < (SMAX)) LD2(UP, bp, (s) + 5);                                \
      bf16x8 a0 = *(const bf16x8*)((aBase) + 64 * (s));                          \
      bf16x8 a1 = *(const bf16x8*)((aBase) + 16 * (STRIDE) + 64 * (s));          \
      bf16x8 a2 = *(const bf16x8*)((aBase) + 32 * (STRIDE) + 64 * (s));          \
      ac[0][0] = mfma16(a0, UC[0], ac[0][0]);                                    \
      ac[1][0] = mfma16(a1, UC[0], ac[1][0]);                                    \
      ac[2][0] = mfma16(a2, UC[0], ac[2][0]);                                    \
      ac[0][1] = mfma16(a0, UC[1], ac[0][1]);                                    \
      ac[1][1] = mfma16(a1, UC[1], ac[1][1]);                                    \
      ac[2][1] = mfma16(a2, UC[1], ac[2][1]); }

// ---------------------------------------------------------------------------
// Table kernel (R13 structure, deeper pipeline): TA=48, 8 waves of 48x32.
// Distance-5 rotating B-prefetch (6 buffers, ~300cy lead > loaded-L2 latency)
// + s0-s4 cross-barrier hoists at every stage boundary. LDS 77KB -> 2 blk/CU.
// ---------------------------------------------------------------------------
__global__ __launch_bounds__(NTHREADS, 4)
void table_main(const float* __restrict__ r, const float* __restrict__ xyz,
                const float* __restrict__ b1, const float* __restrict__ b2,
                const float* __restrict__ W3, const float* __restrict__ b3,
                float* __restrict__ Etab,
                const unsigned short* __restrict__ wt1, const unsigned short* __restrict__ wt2) {
    __shared__ __align__(16) char cNI[TA * SNI_STRIDE];  // 49920 B
    __shared__ __align__(16) char cH[TA * SH_STRIDE];    // 25344 B
    __shared__ float sOut[P_ * TA];

    const int tid  = threadIdx.x;
    const int lane = tid & 63;
    const int w    = tid >> 6;        // wave id: owns cols [w*32, w*32+32)
    const int aB   = blockIdx.x * TA; // node-row base
    const int rA   = lane & 15;
    const int q16  = 16 * (lane >> 4);

    if (tid < P_ * TA) sOut[tid] = 0.f;

    const size_t bofs = (size_t)(w * 2 * 64 + lane) * 8;
    bf16x8 u0[2], u1[2], u2[2], u3[2], u4[2], u5[2];   // 6-buffer rotation

    // Hoist p=0 L1 s0-s4 above the staging + barrier.
    LD2(u0, wt1 + bofs, 0);
    LD2(u1, wt1 + bofs, 1);
    LD2(u2, wt1 + bofs, 2);
    LD2(u3, wt1 + bofs, 3);
    LD2(u4, wt1 + bofs, 4);

    // ---- stage node_input row t = [r[t]+r[t+2], r[t+1]] -> LDS bf16 ----
#pragma unroll
    for (int it = 0; it < 6; ++it) {
        int c   = it * NTHREADS + tid;       // 3072 chunks of 8 elems
        int row = c >> 6;
        int k0  = (c & 63) * 8;
        int t   = min(aB + row, NT_NODES - 1);   // tail rows: dup (discarded)
        float v[8];
        if (k0 < FR_) {
            const float4* p0 = (const float4*)(r + (size_t)t * FR_ + k0);
            const float4* p2 = (const float4*)(r + (size_t)(t + 2) * FR_ + k0);
            float4 x0 = p0[0], x1 = p0[1], y0 = p2[0], y1 = p2[1];
            v[0] = x0.x + y0.x; v[1] = x0.y + y0.y; v[2] = x0.z + y0.z; v[3] = x0.w + y0.w;
            v[4] = x1.x + y1.x; v[5] = x1.y + y1.y; v[6] = x1.z + y1.z; v[7] = x1.w + y1.w;
        } else {
            const float4* p1 = (const float4*)(r + (size_t)(t + 1) * FR_ + (k0 - FR_));
            float4 x0 = p1[0], x1 = p1[1];
            v[0] = x0.x; v[1] = x0.y; v[2] = x0.z; v[3] = x0.w;
            v[4] = x1.x; v[5] = x1.y; v[6] = x1.z; v[7] = x1.w;
        }
        uint4 pk;
        pk.x = pk2(v[0], v[1]); pk.y = pk2(v[2], v[3]);
        pk.z = pk2(v[4], v[5]); pk.w = pk2(v[6], v[7]);
        *reinterpret_cast<uint4*>(cNI + row * SNI_STRIDE + k0 * 2) = pk;
    }
    __syncthreads();

    for (int p = 0; p < P_; ++p) {
        const unsigned short* bp1 = wt1 + (size_t)p * 131072 + bofs;
        const unsigned short* bp2 = wt2 + (size_t)p * 65536 + bofs;

        // ---------------- layer 1: [48x512] @ [512x256], wave cols w*32.. ----
        const float bias10 = b1[p * H_ + w * 32 + rA];
        const float bias11 = b1[p * H_ + w * 32 + 16 + rA];
        f32x4 acc[3][2];
#pragma unroll
        for (int mt = 0; mt < 3; ++mt) {
            acc[mt][0] = (f32x4){bias10, bias10, bias10, bias10};
            acc[mt][1] = (f32x4){bias11, bias11, bias11, bias11};
        }
        {
            const char* aBase = cNI + rA * SNI_STRIDE + q16;
            // u0..u4 = s0..s4 hoisted across the barrier; buf[s%6], pf s+5
            GSTEP( 0, 16, u0, u5, bp1, aBase, SNI_STRIDE, acc);
            GSTEP( 1, 16, u1, u0, bp1, aBase, SNI_STRIDE, acc);
            GSTEP( 2, 16, u2, u1, bp1, aBase, SNI_STRIDE, acc);
            GSTEP( 3, 16, u3, u2, bp1, aBase, SNI_STRIDE, acc);
            GSTEP( 4, 16, u4, u3, bp1, aBase, SNI_STRIDE, acc);
            GSTEP( 5, 16, u5, u4, bp1, aBase, SNI_STRIDE, acc);
            GSTEP( 6, 16, u0, u5, bp1, aBase, SNI_STRIDE, acc);
            GSTEP( 7, 16, u1, u0, bp1, aBase, SNI_STRIDE, acc);
            GSTEP( 8, 16, u2, u1, bp1, aBase, SNI_STRIDE, acc);
            GSTEP( 9, 16, u3, u2, bp1, aBase, SNI_STRIDE, acc);
            GSTEP(10, 16, u4, u3, bp1, aBase, SNI_STRIDE, acc);
            GSTEP(11, 16, u5, u4, bp1, aBase, SNI_STRIDE, acc);
            GSTEP(12, 16, u0, u5, bp1, aBase, SNI_STRIDE, acc);
            GSTEP(13, 16, u1, u0, bp1, aBase, SNI_STRIDE, acc);
            GSTEP(14, 16, u2, u1, bp1, aBase, SNI_STRIDE, acc);
            GSTEP(15, 16, u3, u2, bp1, aBase, SNI_STRIDE, acc);
        }
        // Hoist L2 s0-s4 loads above the tanh epilogue + barrier.
        LD2(u0, bp2, 0);
        LD2(u1, bp2, 1);
        LD2(u2, bp2, 2);
        LD2(u3, bp2, 3);
        LD2(u4, bp2, 4);
        {   // tanh + packed bf16 -> cH (D layout: row = 4*(l>>4)+i, col = l&15)
#pragma unroll
            for (int nt = 0; nt < 2; ++nt) {
                int col = w * 32 + nt * 16 + rA;
#pragma unroll
                for (int mt = 0; mt < 3; ++mt) {
                    float t0 = fast_tanh(acc[mt][nt][0]);
                    float t1 = fast_tanh(acc[mt][nt][1]);
                    float t2 = fast_tanh(acc[mt][nt][2]);
                    float t3 = fast_tanh(acc[mt][nt][3]);
                    unsigned int u01 = pk2(t0, t1);
                    unsigned int u23 = pk2(t2, t3);
                    char* base = cH + (mt * 16 + (lane >> 4) * 4) * SH_STRIDE + col * 2;
                    *(unsigned short*)(base)                 = (unsigned short)(u01 & 0xffff);
                    *(unsigned short*)(base + SH_STRIDE)     = (unsigned short)(u01 >> 16);
                    *(unsigned short*)(base + 2 * SH_STRIDE) = (unsigned short)(u23 & 0xffff);
                    *(unsigned short*)(base + 3 * SH_STRIDE) = (unsigned short)(u23 >> 16);
                }
            }
        }
        __syncthreads();

        // ---------------- layer 2: [48x256] @ [256x256] ----------------
        const float bias20 = b2[p * H_ + w * 32 + rA];
        const float bias21 = b2[p * H_ + w * 32 + 16 + rA];
        f32x4 acc2[3][2];
#pragma unroll
        for (int mt = 0; mt < 3; ++mt) {
            acc2[mt][0] = (f32x4){bias20, bias20, bias20, bias20};
            acc2[mt][1] = (f32x4){bias21, bias21, bias21, bias21};
        }
        {
            const char* aBase = cH + rA * SH_STRIDE + q16;
            // u0..u4 = s0..s4 hoisted across the barrier
            GSTEP(0, 8, u0, u5, bp2, aBase, SH_STRIDE, acc2);
            GSTEP(1, 8, u1, u0, bp2, aBase, SH_STRIDE, acc2);
            GSTEP(2, 8, u2, u1, bp2, aBase, SH_STRIDE, acc2);
            GSTEP(3, 8, u3, u2, bp2, aBase, SH_STRIDE, acc2);
            GSTEP(4, 8, u4, u3, bp2, aBase, SH_STRIDE, acc2);
            GSTEP(5, 8, u5, u4, bp2, aBase, SH_STRIDE, acc2);
            GSTEP(6, 8, u0, u5, bp2, aBase, SH_STRIDE, acc2);
            GSTEP(7, 8, u1, u0, bp2, aBase, SH_STRIDE, acc2);
        }
        // Hoist next-p L1 s0-s4 above the layer-3 epilogue + barrier.
        if (p < P_ - 1) {
            LD2(u0, bp1 + 131072, 0);
            LD2(u1, bp1 + 131072, 1);
            LD2(u2, bp1 + 131072, 2);
            LD2(u3, bp1 + 131072, 3);
            LD2(u4, bp1 + 131072, 4);
        }

        // ---- layer 3: out[p][row] = sum_n tanh(acc2)[row][n]*w3[n], DPP ----
        {
            const float* w3p = W3 + p * H_;
            float prt[12];
#pragma unroll
            for (int k = 0; k < 12; ++k) prt[k] = 0.f;
#pragma unroll
            for (int nt = 0; nt < 2; ++nt) {
                float wv = w3p[w * 32 + nt * 16 + rA];
#pragma unroll
                for (int mt = 0; mt < 3; ++mt)
#pragma unroll
                    for (int i = 0; i < 4; ++i)
                        prt[mt * 4 + i] += fast_tanh(acc2[mt][nt][i]) * wv;
            }
#pragma unroll
            for (int k = 0; k < 12; ++k) DPP_SUM16(prt[k]);
            if (rA == 0) {
                int rg = (lane >> 4) * 4;
#pragma unroll
                for (int mt = 0; mt < 3; ++mt)
#pragma unroll
                    for (int i = 0; i < 4; ++i)
                        atomicAdd(&sOut[p * TA + mt * 16 + rg + i], prt[mt * 4 + i]);
            }
        }
        __syncthreads();   // cH reads done (next p overwrites) + sOut[p] visible
    }

    // ---------------- geometry + energy -> Etab[t] ----------------
    if (tid < TA && (aB + tid) < NT_NODES) {
        int t = aB + tid;
        float ax = xyz[3 * t],     ay = xyz[3 * t + 1], az = xyz[3 * t + 2];
        float bx = xyz[3 * t + 3], by = xyz[3 * t + 4], bz = xyz[3 * t + 5];
        float cx = xyz[3 * t + 6], cy = xyz[3 * t + 7], cz = xyz[3 * t + 8];
        float v1x = bx - ax, v1y = by - ay, v1z = bz - az;
        float v2x = cx - bx, v2y = cy - by, v2z = cz - bz;
        float dot = -(v1x * v2x + v1y * v2y + v1z * v2z);
        float n1  = v1x * v1x + v1y * v1y + v1z * v1z;
        float n2  = v2x * v2x + v2y * v2y + v2z * v2z;
        float th  = acosf((dot / sqrtf(n1 * n2)) / 1.000001f);

        float o0 = sOut[0 * TA + tid] + b3[0], o1 = sOut[1 * TA + tid] + b3[1];
        float o2 = sOut[2 * TA + tid] + b3[2], o3 = sOut[3 * TA + tid] + b3[3];
        float o4 = sOut[4 * TA + tid] + b3[4], o5 = sOut[5 * TA + tid] + b3[5];
        float t0h = (1.38243827f + o0); t0h *= t0h;
        float kh  = (3.16227766f + o1); kh  *= kh;
        float d   = th - t0h;
        float E   = 0.5f * kh * d * d;
        float t0c = o2 * o2, kc = o3 * o3;
        float dc  = th - t0c;
        E += 0.5f * kc * dc * dc * dc;
        float t0q = o4 * o4, kq = o5 * o5;
        float dq  = th - t0q;
        E += 0.5f * kq * dq * dq * dq * dq;
        Etab[t] = E;
    }
}

// ---------------------------------------------------------------------------
// Per-angle pass: regular angles take E from the table, bin into LDS segments.
// ---------------------------------------------------------------------------
#define SEG_ANG 2048
__global__ void seg_kernel(const int* __restrict__ ang, const float* __restrict__ Etab,
                           const int* __restrict__ prefix, float* __restrict__ out) {
    __shared__ float sSeg[BSEG];
    __shared__ int   sPre[BSEG + 1];
    int tid = threadIdx.x;
    if (tid < BSEG) sSeg[tid] = 0.f;
    if (tid <= BSEG) sPre[tid] = prefix[tid];
    __syncthreads();
    int base = blockIdx.x * SEG_ANG;
#pragma unroll
    for (int i = 0; i < SEG_ANG / 256; ++i) {
        int a = base + i * 256 + tid;
        if (a < A_TOTAL) {
            int i0 = ang[3 * a], i1 = ang[3 * a + 1], i2 = ang[3 * a + 2];
            if (i1 == i0 + 1 && i2 == i0 + 2 && i0 >= 0 && i0 < NT_NODES) {
                float E = Etab[i0];
                int lo = 0, hi = BSEG - 1;
                while (lo < hi) { int mid = (lo + hi + 1) >> 1; if (sPre[mid] <= a) lo = mid; else hi = mid - 1; }
                atomicAdd(&sSeg[lo], E);
            }
        }
    }
    __syncthreads();
    if (tid < BSEG) {
        float v = sSeg[tid];
        if (v != 0.f) atomicAdd(out + tid, v);
    }
}

// ---------------------------------------------------------------------------
// Fallback: any non-regular angle gets an exact scalar f32 MLP (never
// triggers for this generator; keeps arbitrary-input correctness).
// ---------------------------------------------------------------------------
__global__ void fb_kernel(const float* __restrict__ r, const float* __restrict__ xyz,
                          const int* __restrict__ ang,
                          const float* __restrict__ W1, const float* __restrict__ b1,
                          const float* __restrict__ W2, const float* __restrict__ b2,
                          const float* __restrict__ W3, const float* __restrict__ b3,
                          const int* __restrict__ prefix, float* __restrict__ out) {
    int gid = blockIdx.x * blockDim.x + threadIdx.x;
    int stride = gridDim.x * blockDim.x;
    for (int a = gid; a < A_TOTAL; a += stride) {
        int i0 = ang[3 * a], i1 = ang[3 * a + 1], i2 = ang[3 * a + 2];
        if (i1 == i0 + 1 && i2 == i0 + 2 && i0 >= 0 && i0 < NT_NODES) continue;  // table path
        float ni[DIN_];
        for (int k = 0; k < FR_; ++k) ni[k] = r[(size_t)i0 * FR_ + k] + r[(size_t)i2 * FR_ + k];
        for (int k = 0; k < FR_; ++k) ni[FR_ + k] = r[(size_t)i1 * FR_ + k];
        float o[P_];
        for (int p = 0; p < P_; ++p) {
            float h1[H_], h2[H_];
            for (int j = 0; j < H_; ++j) {
                float s = b1[p * H_ + j];
                for (int i = 0; i < DIN_; ++i) s += ni[i] * W1[((size_t)p * DIN_ + i) * H_ + j];
                h1[j] = tanhf(s);
            }
            for (int j = 0; j < H_; ++j) {
                float s = b2[p * H_ + j];
                for (int i = 0; i < H_; ++i) s += h1[i] * W2[((size_t)p * H_ + i) * H_ + j];
                h2[j] = tanhf(s);
            }
            float s = b3[p];
            for (int i = 0; i < H_; ++i) s += h2[i] * W3[p * H_ + i];
            o[p] = s;
        }
        float ax = xyz[3 * i0], ay = xyz[3 * i0 + 1], az = xyz[3 * i0 + 2];
        float bx = xyz[3 * i1], by = xyz[3 * i1 + 1], bz = xyz[3 * i1 + 2];
        float cx = xyz[3 * i2], cy = xyz[3 * i2 + 1], cz = xyz[3 * i2 + 2];
        float v1x = bx - ax, v1y = by - ay, v1z = bz - az;
        float v2x = cx - bx, v2y = cy - by, v2z = cz - bz;
        float dot = -(v1x * v2x + v1y * v2y + v1z * v2z);
        float n1  = v1x * v1x + v1y * v1y + v1z * v1z;
        float n2  = v2x * v2x + v2y * v2y + v2z * v2z;
        float th  = acosf((dot / sqrtf(n1 * n2)) / 1.000001f);
        float t0h = (1.38243827f + o[0]); t0h *= t0h;
        float kh  = (3.16227766f + o[1]); kh  *= kh;
        float d   = th - t0h;
        float E   = 0.5f * kh * d * d;
        float t0c = o[2] * o[2], kc = o[3] * o[3];
        float dc  = th - t0c;
        E += 0.5f * kc * dc * dc * dc;
        float t0q = o[4] * o[4], kq = o[5] * o[5];
        float dq  = th - t0q;
        E += 0.5f * kq * dq * dq * dq * dq;
        int lo = 0, hi = BSEG - 1;
        while (lo < hi) { int mid = (lo + hi + 1) >> 1; if (prefix[mid] <= a) lo = mid; else hi = mid - 1; }
        atomicAdd(out + lo, E);
    }
}

extern "C" void kernel_launch(void* const* d_in, const int* in_sizes, int n_in,
                              void* d_out, int out_size, void* d_ws, size_t ws_size,
                              hipStream_t stream) {
    const float* r   = (const float*)d_in[0];
    const float* xyz = (const float*)d_in[1];
    const int*   ang = (const int*)d_in[2];
    const int*   na  = (const int*)d_in[3];
    const float* W1  = (const float*)d_in[4];
    const float* b1  = (const float*)d_in[5];
    const float* W2  = (const float*)d_in[6];
    const float* b2  = (const float*)d_in[7];
    const float* W3  = (const float*)d_in[8];
    const float* b3  = (const float*)d_in[9];
    float* out = (float*)d_out;

    char* ws = (char*)d_ws;
    int* prefix          = (int*)ws;                                        // 101 ints
    unsigned short* wt1  = (unsigned short*)(ws + 512);                     // 1.5 MB
    unsigned short* wt2  = (unsigned short*)(ws + 512 + 1572864);           // 0.75 MB
    float* Etab          = (float*)(ws + 512 + 1572864 + 786432);           // 200 KB

    prep_kernel<<<576, 256, 0, stream>>>(W1, W2, na, out, prefix, wt1, wt2);
    int nblk = (NT_NODES + TA - 1) / TA;   // 1042 blocks over unique triples
    table_main<<<nblk, NTHREADS, 0, stream>>>(r, xyz, b1, b2, W3, b3, Etab, wt1, wt2);
    seg_kernel<<<(A_TOTAL + SEG_ANG - 1) / SEG_ANG, 256, 0, stream>>>(ang, Etab, prefix, out);
    fb_kernel<<<32, 256, 0, stream>>>(r, xyz, ang, W1, b1, W2, b2, W3, b3, prefix, out);
}